// Round 10
// baseline (1610.071 us; speedup 1.0000x reference)
//
#include <hip/hip_runtime.h>

// R10: persistent mega-kernel. prep -> embed -> gnn1 -> gnn2 -> gnn3 -> readout
// in ONE 1024-block launch with spin grid-barriers (counter+generation,
// agent-scope acq/rel: RMW-release emits per-XCD buffer_wbl2, acquire emits
// buffer_inv -> cross-XCD visibility per G16). Co-residency by construction:
// launch_bounds(256,4) caps VGPR at 128, smem 25KB <= 40KB/block @ 4/CU.
// Phase bodies are the verified R9/R8 ones. Intermediates h[b][f][n] fp32.
// GNN layer exact rewrite: h' = relu( agg(h) @ W + rowsum*b ).
// fp32 split a = hi + lo (bf16); 3 MFMAs: hi*wh + hi*wl + lo*wh.
//
// MFMA 16x16x32 bf16 layouts (verified m89/m120):
//   A (MxK): m = lane&15, k = quad*8 + j    B (KxN): n = lane&15, k = quad*8 + j
//   C/D: col(N) = lane&15, row(M) = quad*4 + reg

typedef __attribute__((ext_vector_type(8))) short bf16x8;
typedef __attribute__((ext_vector_type(4))) float f32x4;
#define MFMA(a, b, c) __builtin_amdgcn_mfma_f32_16x16x32_bf16(a, b, c, 0, 0, 0)

// barrier with LDS visibility but WITHOUT draining global loads:
// s_waitcnt imm 0xC07F = vmcnt(63) expcnt(7) lgkmcnt(0)
__device__ inline void block_sync_lgkm() {
    asm volatile("" ::: "memory");
    __builtin_amdgcn_s_waitcnt(0xC07F);
    __builtin_amdgcn_s_barrier();
    asm volatile("" ::: "memory");
}

#define NBLK 1024u
__device__ inline void grid_barrier(unsigned* cnt, unsigned* gen) {
    __syncthreads();
    __threadfence();
    if (threadIdx.x == 0) {
        const unsigned g = __hip_atomic_load(gen, __ATOMIC_RELAXED, __HIP_MEMORY_SCOPE_AGENT);
        const unsigned prev = __hip_atomic_fetch_add(cnt, 1u, __ATOMIC_ACQ_REL, __HIP_MEMORY_SCOPE_AGENT);
        if (prev == NBLK - 1u) {
            __hip_atomic_store(cnt, 0u, __ATOMIC_RELAXED, __HIP_MEMORY_SCOPE_AGENT);
            __hip_atomic_store(gen, g + 1u, __ATOMIC_RELEASE, __HIP_MEMORY_SCOPE_AGENT);
        } else {
            while (__hip_atomic_load(gen, __ATOMIC_ACQUIRE, __HIP_MEMORY_SCOPE_AGENT) == g) {
                __builtin_amdgcn_s_sleep(16);
            }
        }
    }
    __syncthreads();
    __threadfence();
}

__device__ inline ushort bf16h(float x) {
    unsigned u = __float_as_uint(x);
    return (ushort)((u + 0x7fffu + ((u >> 16) & 1u)) >> 16);
}
__device__ inline void split_bf16(float x, ushort& hi, ushort& lo) {
    hi = bf16h(x);
    lo = bf16h(x - __uint_as_float(((unsigned)hi) << 16));
}
// packed (hi16 << 16) | lo16 ; hi = RNE, lo = truncation
__device__ inline unsigned pack_split(float x) {
    unsigned u = __float_as_uint(x);
    unsigned hi = (u + 0x7fffu + ((u >> 16) & 1u)) >> 16;
    float r = x - __uint_as_float(hi << 16);
    return (hi << 16) | (__float_as_uint(r) >> 16);
}
// 8 packed u32 (stride 65) -> hi/lo bf16x8 fragments
__device__ inline void frag_packed(const unsigned* bp, bf16x8& bh, bf16x8& bl) {
    unsigned p[8];
#pragma unroll
    for (int j = 0; j < 8; j++) p[j] = bp[j * 65];
    union { bf16x8 v; unsigned d[4]; } H, L;
#pragma unroll
    for (int j = 0; j < 4; j++) {
        const unsigned e = p[2 * j], o = p[2 * j + 1];
        H.d[j] = (o & 0xFFFF0000u) | (e >> 16);
        L.d[j] = (o << 16) | (e & 0xFFFFu);
    }
    bh = H.v; bl = L.v;
}

// ---- GNN phase (R9 body): quarter-pipelined, drain-free intra-block barriers ----
template <int K, bool MEAN>
__device__ __forceinline__ void gnn_phase(
    unsigned* smem, int b, int row, int tid,
    const float* __restrict__ hin, const ushort* __restrict__ wf,
    const float* __restrict__ bias, float* __restrict__ hout,
    float* __restrict__ gsum)
{
    constexpr int NQ = K / 32;
    unsigned* AsB[2] = { smem, smem + 2080 };
    const int lane = tid & 63, w = tid >> 6, quad = lane >> 4, nl = lane & 15;
    const int kp = tid >> 4, nq = tid & 15;
    const float* hb = hin + (size_t)b * K * 4096;
    const int rowu = (row > 0) ? row - 1 : row;
    const int rowd = (row < 63) ? row + 1 : row;
    const float su = (row > 0) ? 1.f : 0.f;
    const float sd = (row < 63) ? 1.f : 0.f;
    float inv[4];
#pragma unroll
    for (int i = 0; i < 4; i++) {
        const int n = nq * 4 + i;
        const int deg = (row > 0) + (row < 63) + (n > 0) + (n < 63);
        inv[i] = 1.f / ((float)deg + 1e-6f);
    }

    const ushort* wfl = wf + lane * 8;
    f32x4 acc[4][2];
#pragma unroll
    for (int nt = 0; nt < 4; nt++) {
        acc[nt][0] = (f32x4){0.f, 0.f, 0.f, 0.f};
        acc[nt][1] = (f32x4){0.f, 0.f, 0.f, 0.f};
    }

    float4 S[6];
    bf16x8 V[2][2];

    auto sload = [&](int q) {
#pragma unroll
        for (int it = 0; it < 2; it++) {
            const int kg = q * 32 + it * 16 + kp;
            const float* pk = hb + ((size_t)kg << 12) + nq * 4;
            S[it * 3 + 0] = *(const float4*)(pk + row * 64);
            S[it * 3 + 1] = *(const float4*)(pk + rowu * 64);
            S[it * 3 + 2] = *(const float4*)(pk + rowd * 64);
        }
    };
    auto wload = [&](int q) {
#pragma unroll
        for (int ftl = 0; ftl < 2; ftl++) {
            V[ftl][0] = *(const bf16x8*)(wfl + ((q * 8 + 2 * w + ftl) * 2) * 512);
            V[ftl][1] = *(const bf16x8*)(wfl + ((q * 8 + 2 * w + ftl) * 2 + 1) * 512);
        }
    };
    auto stage = [&](unsigned* Ab) {
#pragma unroll
        for (int it = 0; it < 2; it++) {
            const int kl = it * 16 + kp;
            const float4 c4 = S[it * 3 + 0];
            const float4 u4 = S[it * 3 + 1];
            const float4 d4 = S[it * 3 + 2];
            const float pw = __shfl_up(c4.w, 1);
            const float nx = __shfl_down(c4.x, 1);
            const float lx = (nq > 0) ? pw : 0.f;
            const float rw = (nq < 15) ? nx : 0.f;
            unsigned* ap = Ab + kl * 65 + nq * 4;
            ap[0] = pack_split((su * u4.x + sd * d4.x + lx + c4.y) * inv[0]);
            ap[1] = pack_split((su * u4.y + sd * d4.y + c4.x + c4.z) * inv[1]);
            ap[2] = pack_split((su * u4.z + sd * d4.z + c4.y + c4.w) * inv[2]);
            ap[3] = pack_split((su * u4.w + sd * d4.w + c4.z + rw) * inv[3]);
        }
    };
    auto consume = [&](const unsigned* Ab) {
#pragma unroll
        for (int nt = 0; nt < 4; nt++) {
            const unsigned* bp = Ab + (quad * 8) * 65 + nt * 16 + nl;
            bf16x8 bh, bl; frag_packed(bp, bh, bl);
            acc[nt][0] = MFMA(V[0][0], bh, acc[nt][0]);
            acc[nt][0] = MFMA(V[0][0], bl, acc[nt][0]);
            acc[nt][0] = MFMA(V[0][1], bh, acc[nt][0]);
            acc[nt][1] = MFMA(V[1][0], bh, acc[nt][1]);
            acc[nt][1] = MFMA(V[1][0], bl, acc[nt][1]);
            acc[nt][1] = MFMA(V[1][1], bh, acc[nt][1]);
        }
    };

    wload(0);
    sload(0);
    stage(AsB[0]);
    sload(1);
    block_sync_lgkm();

#pragma unroll
    for (int q = 0; q < NQ; q++) {
        consume(AsB[q & 1]);
        if (q + 1 < NQ) {
            wload(q + 1);
            stage(AsB[(q + 1) & 1]);
            if (q + 2 < NQ) sload(q + 2);
            block_sync_lgkm();
        }
    }

    if (!MEAN) {
#pragma unroll
        for (int ftl = 0; ftl < 2; ftl++) {
            const int fb = 32 * w + 16 * ftl + quad * 4;
            const float b0 = bias[fb], b1 = bias[fb + 1], b2 = bias[fb + 2], b3 = bias[fb + 3];
#pragma unroll
            for (int nt = 0; nt < 4; nt++) {
                const int n = 16 * nt + nl;
                const int deg = (row > 0) + (row < 63) + (n > 0) + (n < 63);
                const float rs = (float)deg / ((float)deg + 1e-6f);
                float* op = hout + ((size_t)(b * 128 + fb) << 12) + row * 64 + n;
                op[0]        = fmaxf(acc[nt][ftl][0] + rs * b0, 0.f);
                op[1u << 12] = fmaxf(acc[nt][ftl][1] + rs * b1, 0.f);
                op[2u << 12] = fmaxf(acc[nt][ftl][2] + rs * b2, 0.f);
                op[3u << 12] = fmaxf(acc[nt][ftl][3] + rs * b3, 0.f);
            }
        }
    } else {
#pragma unroll
        for (int ftl = 0; ftl < 2; ftl++) {
            const int fb = 32 * w + 16 * ftl + quad * 4;
#pragma unroll
            for (int reg = 0; reg < 4; reg++) {
                const float bv = bias[fb + reg];
                float v = 0.f;
#pragma unroll
                for (int nt = 0; nt < 4; nt++) {
                    const int n = 16 * nt + nl;
                    const int deg = (row > 0) + (row < 63) + (n > 0) + (n < 63);
                    const float rs = (float)deg / ((float)deg + 1e-6f);
                    v += fmaxf(acc[nt][ftl][reg] + rs * bv, 0.f);
                }
                v += __shfl_xor(v, 1); v += __shfl_xor(v, 2);
                v += __shfl_xor(v, 4); v += __shfl_xor(v, 8);
                if (nl == 0) atomicAdd(&gsum[b * 128 + fb + reg], v * (1.f / 4096.f));
            }
        }
    }
}

__global__ __launch_bounds__(256, 4) void mega_kernel(
    const float* __restrict__ obs,
    const float* __restrict__ e1w, const float* __restrict__ e1b,
    const float* __restrict__ e2w, const float* __restrict__ e2b,
    const float* __restrict__ g1w, const float* __restrict__ g1b,
    const float* __restrict__ g2w, const float* __restrict__ g2b,
    const float* __restrict__ g3w, const float* __restrict__ g3b,
    const float* __restrict__ r1w, const float* __restrict__ r1b,
    const float* __restrict__ r2w, const float* __restrict__ r2b,
    float* __restrict__ out, float* __restrict__ h0, float* __restrict__ h1,
    float* __restrict__ h2, float* __restrict__ gsum, ushort* __restrict__ wfb,
    unsigned* __restrict__ bar)
{
    __shared__ __align__(16) unsigned smem[6240];   // 25 KB: embed 6240, gnn 2x2080
    const int blk = blockIdx.x, tid = threadIdx.x;
    // XCD-contiguous remap (bijection on [0,1024)): consecutive rows same XCD
    const int bid = ((blk & 7) << 7) | (blk >> 3);
    const int b = bid >> 6, row = bid & 63;
    const int lane = tid & 63, w = tid >> 6, quad = lane >> 4, nl = lane & 15;
    const int cp = tid >> 4, nq = tid & 15;
    unsigned* cnt = bar;
    unsigned* gen = bar + 1;

    // ---------------- P0: weight frag prep (e1,e2,g1,g2,g3) + gsum zero ----------------
    if (blk < 23) {
        const int u = blk * 4 + (tid >> 6);
        const int l = tid & 63;
        const float* src; int K, N, kc, t; ushort* dst;
        if (u < 4)       { src = e1w; K = 16;  N = 64;  kc = 0; t = u; dst = wfb; }
        else if (u < 12) { src = e2w; K = 64;  N = 64;  int v = u - 4;  kc = v >> 2; t = v & 3; dst = wfb + 4096; }
        else if (u < 28) { src = g1w; K = 64;  N = 128; int v = u - 12; kc = v >> 3; t = v & 7; dst = wfb + 12288; }
        else if (u < 60) { src = g2w; K = 128; N = 128; int v = u - 28; kc = v >> 3; t = v & 7; dst = wfb + 28672; }
        else             { src = g3w; K = 128; N = 128; int v = u - 60; kc = v >> 3; t = v & 7; dst = wfb + 61440; }
        const int T = (N == 64) ? 4 : 8;
        ushort* uh = dst + ((kc * T + t) * 2 + 0) * 512 + l * 8;
        ushort* ul = dst + ((kc * T + t) * 2 + 1) * 512 + l * 8;
        const int f = t * 16 + (l & 15);
        const int kb = kc * 32 + ((l >> 4) << 3);
#pragma unroll
        for (int j = 0; j < 8; j++) {
            const int k = kb + j;
            const float wv = (k < K) ? src[k * N + f] : 0.f;
            ushort hi, lo; split_bf16(wv, hi, lo);
            uh[j] = hi; ul[j] = lo;
        }
    } else if (blk < 31) {
        gsum[(blk - 23) * 256 + tid] = 0.f;
    }
    grid_barrier(cnt, gen);

    // ---------------- P1: embed (all blocks) ----------------
    {
        const float4 x4 = *(const float4*)(obs + ((size_t)(b * 16 + cp) << 12) + row * 64 + nq * 4);
        unsigned* Xs = smem;
        unsigned* Hs = smem + 2080;
        unsigned* xp = Xs + cp * 65 + nq * 4;
        xp[0] = pack_split(x4.x); xp[1] = pack_split(x4.y);
        xp[2] = pack_split(x4.z); xp[3] = pack_split(x4.w);
        unsigned* zp = Xs + (16 + cp) * 65 + nq * 4;
        zp[0] = 0u; zp[1] = 0u; zp[2] = 0u; zp[3] = 0u;
        __syncthreads();

        {   // layer 1: wave w -> mid-feats 16w..16w+15
            const ushort* wp = wfb + lane * 8;
            const bf16x8 wh = *(const bf16x8*)(wp + (w * 2) * 512);
            const bf16x8 wl = *(const bf16x8*)(wp + (w * 2 + 1) * 512);
#pragma unroll
            for (int nt = 0; nt < 4; nt++) {
                const unsigned* bp = Xs + (quad * 8) * 65 + nt * 16 + nl;
                bf16x8 bh, bl; frag_packed(bp, bh, bl);
                f32x4 c = {0.f, 0.f, 0.f, 0.f};
                c = MFMA(wh, bh, c); c = MFMA(wh, bl, c); c = MFMA(wl, bh, c);
#pragma unroll
                for (int reg = 0; reg < 4; reg++) {
                    const int fm = 16 * w + quad * 4 + reg;
                    Hs[fm * 65 + nt * 16 + nl] = pack_split(fmaxf(c[reg] + e1b[fm], 0.f));
                }
            }
        }
        __syncthreads();

        // layer 2: K=64 (2 kc)
        const ushort* e2f = wfb + 4096;
        f32x4 a2[4];
#pragma unroll
        for (int nt = 0; nt < 4; nt++) a2[nt] = (f32x4){0.f, 0.f, 0.f, 0.f};
#pragma unroll
        for (int kc = 0; kc < 2; kc++) {
            const ushort* wp = e2f + lane * 8;
            const bf16x8 wh = *(const bf16x8*)(wp + ((kc * 4 + w) * 2) * 512);
            const bf16x8 wl = *(const bf16x8*)(wp + ((kc * 4 + w) * 2 + 1) * 512);
#pragma unroll
            for (int nt = 0; nt < 4; nt++) {
                const unsigned* bp = Hs + (kc * 32 + quad * 8) * 65 + nt * 16 + nl;
                bf16x8 bh, bl; frag_packed(bp, bh, bl);
                a2[nt] = MFMA(wh, bh, a2[nt]);
                a2[nt] = MFMA(wh, bl, a2[nt]);
                a2[nt] = MFMA(wl, bh, a2[nt]);
            }
        }
#pragma unroll
        for (int reg = 0; reg < 4; reg++) {
            const int f = 16 * w + quad * 4 + reg;
            const float bv = e2b[f];
#pragma unroll
            for (int nt = 0; nt < 4; nt++)
                h0[((size_t)(b * 64 + f) << 12) + row * 64 + nt * 16 + nl] =
                    fmaxf(a2[nt][reg] + bv, 0.f);
        }
    }
    grid_barrier(cnt, gen);

    // ---------------- P2-P4: GNN layers ----------------
    gnn_phase<64, false>(smem, b, row, tid, h0, wfb + 12288, g1b, h1, nullptr);
    grid_barrier(cnt, gen);
    gnn_phase<128, false>(smem, b, row, tid, h1, wfb + 28672, g2b, h2, nullptr);
    grid_barrier(cnt, gen);
    gnn_phase<128, true>(smem, b, row, tid, h2, wfb + 61440, g3b, nullptr, gsum);
    grid_barrier(cnt, gen);

    // ---------------- P5: readout (blocks 0..15) ----------------
    if (blk < 16) {
        float* gs = (float*)smem;
        float* g2 = gs + 128;
        if (tid < 128) gs[tid] = gsum[blk * 128 + tid];
        __syncthreads();
        float a = r1b[tid];
#pragma unroll 16
        for (int k = 0; k < 128; k++) a = fmaf(gs[k], r1w[k * 256 + tid], a);
        g2[tid] = fmaxf(a, 0.f);
        __syncthreads();
        float a2 = r2b[tid];
#pragma unroll 16
        for (int k = 0; k < 256; k++) a2 = fmaf(g2[k], r2w[k * 256 + tid], a2);
        out[blk * 256 + tid] = fmaxf(a2, 0.f);
    }
}

extern "C" void kernel_launch(void* const* d_in, const int* in_sizes, int n_in,
                              void* d_out, int out_size, void* d_ws, size_t ws_size,
                              hipStream_t stream)
{
    const float* obs = (const float*)d_in[0];
    const float* e1w = (const float*)d_in[1];
    const float* e1b = (const float*)d_in[2];
    const float* e2w = (const float*)d_in[3];
    const float* e2b = (const float*)d_in[4];
    const float* g1w = (const float*)d_in[5];
    const float* g1b = (const float*)d_in[6];
    const float* g2w = (const float*)d_in[7];
    const float* g2b = (const float*)d_in[8];
    const float* g3w = (const float*)d_in[9];
    const float* g3b = (const float*)d_in[10];
    const float* r1w = (const float*)d_in[11];
    const float* r1b = (const float*)d_in[12];
    const float* r2w = (const float*)d_in[13];
    const float* r2b = (const float*)d_in[14];
    float* out = (float*)d_out;
    float* ws = (float*)d_ws;

    float* h0 = ws;                                   // 16 MB
    float* h1 = ws + 4194304;                         // 32 MB
    float* h2 = ws + 4194304 + 8388608;               // 32 MB
    float* gsum = (float*)((char*)d_ws + 80u * 1024u * 1024u);          // 8 KB
    ushort* wfb = (ushort*)((char*)d_ws + 80u * 1024u * 1024u + 8192u); // 184 KB
    unsigned* bar = (unsigned*)((char*)d_ws + 80u * 1024u * 1024u + 524288u);

    hipMemsetAsync(bar, 0, 8, stream);   // counter + generation = 0
    hipLaunchKernelGGL(mega_kernel, dim3(1024), dim3(256), 0, stream,
                       obs, e1w, e1b, e2w, e2b, g1w, g1b, g2w, g2b, g3w, g3b,
                       r1w, r1b, r2w, r2b, out, h0, h1, h2, gsum, wfb, bar);
}

// Round 11
// 201.516 us; speedup vs baseline: 7.9898x; 7.9898x over previous
//
#include <hip/hip_runtime.h>

// R11: occupancy fix. Node-split tiles (32 nodes/block), grid 2048, 6 blocks/CU
// -> 24 waves/CU (was 16). R10 counters showed all phases latency-bound
// (VALUBusy ~1%, pipe-sum << duration). Stride-33 [k][n] LDS (conflict-free),
// drain-free lgkm barriers, packed hi|lo split-at-stage, XCD-contig remap
// shared by embed+gnn for producer/consumer L2 affinity.
// Intermediates FEATURE-MAJOR h[b][f][n], n = 64x64 grid.
// GNN layer exact rewrite: h' = relu( agg(h) @ W + rowsum*b ).
// fp32 split a = hi + lo (bf16); 3 MFMAs: hi*wh + hi*wl + lo*wh.
//
// MFMA 16x16x32 bf16 layouts (verified m89/m120):
//   A (MxK): m = lane&15, k = quad*8 + j    B (KxN): n = lane&15, k = quad*8 + j
//   C/D: col(N) = lane&15, row(M) = quad*4 + reg

typedef __attribute__((ext_vector_type(8))) short bf16x8;
typedef __attribute__((ext_vector_type(4))) float f32x4;
#define MFMA(a, b, c) __builtin_amdgcn_mfma_f32_16x16x32_bf16(a, b, c, 0, 0, 0)

// barrier with LDS visibility but WITHOUT draining global loads:
// s_waitcnt imm 0xC07F = vmcnt(63) expcnt(7) lgkmcnt(0)
__device__ inline void block_sync_lgkm() {
    asm volatile("" ::: "memory");
    __builtin_amdgcn_s_waitcnt(0xC07F);
    __builtin_amdgcn_s_barrier();
    asm volatile("" ::: "memory");
}

__device__ inline ushort bf16h(float x) {
    unsigned u = __float_as_uint(x);
    return (ushort)((u + 0x7fffu + ((u >> 16) & 1u)) >> 16);
}
__device__ inline void split_bf16(float x, ushort& hi, ushort& lo) {
    hi = bf16h(x);
    lo = bf16h(x - __uint_as_float(((unsigned)hi) << 16));
}
// packed (hi16 << 16) | lo16 ; hi = RNE, lo = truncation
__device__ inline unsigned pack_split(float x) {
    unsigned u = __float_as_uint(x);
    unsigned hi = (u + 0x7fffu + ((u >> 16) & 1u)) >> 16;
    float r = x - __uint_as_float(hi << 16);
    return (hi << 16) | (__float_as_uint(r) >> 16);
}
// 8 packed u32 (stride ST) -> hi/lo bf16x8 fragments
template <int ST>
__device__ inline void frag_packed(const unsigned* bp, bf16x8& bh, bf16x8& bl) {
    unsigned p[8];
#pragma unroll
    for (int j = 0; j < 8; j++) p[j] = bp[j * ST];
    union { bf16x8 v; unsigned d[4]; } H, L;
#pragma unroll
    for (int j = 0; j < 4; j++) {
        const unsigned e = p[2 * j], o = p[2 * j + 1];
        H.d[j] = (o & 0xFFFF0000u) | (e >> 16);
        L.d[j] = (o << 16) | (e & 0xFFFFu);
    }
    bh = H.v; bl = L.v;
}

// ---- weight pre-split into fragment-ordered bf16 hi/lo planes (+ gsum zero) --
__global__ __launch_bounds__(64) void wprep_kernel(
    const float* __restrict__ e1w, const float* __restrict__ e2w,
    const float* __restrict__ g1w, const float* __restrict__ g2w,
    const float* __restrict__ g3w, ushort* __restrict__ wf,
    float* __restrict__ gsum)
{
    const int blk = blockIdx.x, l = threadIdx.x;
    if (blk >= 92) {                       // 32 blocks x 64 = 2048: zero gsum
        gsum[(blk - 92) * 64 + l] = 0.f;
        return;
    }
    const float* src; int K, N, kc, t; ushort* dst;
    if (blk < 4)        { src = e1w; K = 16;  N = 64;  kc = 0; t = blk;      dst = wf; }
    else if (blk < 12)  { src = e2w; K = 64;  N = 64;  int u = blk - 4;  kc = u >> 2; t = u & 3; dst = wf + 4096; }
    else if (blk < 28)  { src = g1w; K = 64;  N = 128; int u = blk - 12; kc = u >> 3; t = u & 7; dst = wf + 12288; }
    else if (blk < 60)  { src = g2w; K = 128; N = 128; int u = blk - 28; kc = u >> 3; t = u & 7; dst = wf + 28672; }
    else                { src = g3w; K = 128; N = 128; int u = blk - 60; kc = u >> 3; t = u & 7; dst = wf + 61440; }
    const int T = (N == 64) ? 4 : 8;
    ushort* uh = dst + ((kc * T + t) * 2 + 0) * 512 + l * 8;
    ushort* ul = dst + ((kc * T + t) * 2 + 1) * 512 + l * 8;
    const int f = t * 16 + (l & 15);
    const int kb = kc * 32 + ((l >> 4) << 3);
#pragma unroll
    for (int j = 0; j < 8; j++) {
        const int k = kb + j;
        const float w = (k < K) ? src[k * N + f] : 0.f;
        ushort hi, lo; split_bf16(w, hi, lo);
        uh[j] = hi; ul[j] = lo;
    }
}

// ---- embed: 32-node tiles, grid 2048, fused 2-layer MLP via MFMA ----
__global__ __launch_bounds__(256, 6) void embed_kernel(
    const float* __restrict__ obs, const ushort* __restrict__ wf,
    const float* __restrict__ e1b, const float* __restrict__ e2b,
    float* __restrict__ h0)
{
    __shared__ unsigned Xs[32 * 33];   // packed x planes [k][n], k>=16 zeroed
    __shared__ unsigned Hs[64 * 33];   // packed layer-1 activations [f][n]
    const int blk = blockIdx.x, tid = threadIdx.x;
    const int bid = ((blk & 7) << 8) | (blk >> 3);   // XCD-contig remap (11-bit bijection)
    const int b = bid >> 7, row = (bid >> 1) & 63, tile = bid & 1;
    const int gc = tile << 5;
    const int lane = tid & 63, w = tid >> 6, quad = lane >> 4, nl = lane & 15;
    const int cp = tid >> 4, nq = tid & 15;

    {   // stage obs (float2/thread), zero pad planes
        const float2 x2 = *(const float2*)(obs + ((size_t)(b * 16 + cp) << 12) + row * 64 + gc + nq * 2);
        Xs[cp * 33 + nq * 2]            = pack_split(x2.x);
        Xs[cp * 33 + nq * 2 + 1]        = pack_split(x2.y);
        Xs[(16 + cp) * 33 + nq * 2]     = 0u;
        Xs[(16 + cp) * 33 + nq * 2 + 1] = 0u;
    }
    __syncthreads();

    {   // layer 1: wave w -> mid-feats 16w..16w+15
        const ushort* wp = wf + lane * 8;
        const bf16x8 wh = *(const bf16x8*)(wp + (w * 2) * 512);
        const bf16x8 wl = *(const bf16x8*)(wp + (w * 2 + 1) * 512);
#pragma unroll
        for (int nt = 0; nt < 2; nt++) {
            const unsigned* bp = Xs + (quad * 8) * 33 + nt * 16 + nl;
            bf16x8 bh, bl; frag_packed<33>(bp, bh, bl);
            f32x4 c = {0.f, 0.f, 0.f, 0.f};
            c = MFMA(wh, bh, c); c = MFMA(wh, bl, c); c = MFMA(wl, bh, c);
#pragma unroll
            for (int reg = 0; reg < 4; reg++) {
                const int fm = 16 * w + quad * 4 + reg;
                Hs[fm * 33 + nt * 16 + nl] = pack_split(fmaxf(c[reg] + e1b[fm], 0.f));
            }
        }
    }
    __syncthreads();

    // layer 2: K=64 (2 kc)
    const ushort* e2f = wf + 4096;
    f32x4 a2[2];
    a2[0] = (f32x4){0.f, 0.f, 0.f, 0.f};
    a2[1] = (f32x4){0.f, 0.f, 0.f, 0.f};
#pragma unroll
    for (int kc = 0; kc < 2; kc++) {
        const ushort* wp = e2f + lane * 8;
        const bf16x8 wh = *(const bf16x8*)(wp + ((kc * 4 + w) * 2) * 512);
        const bf16x8 wl = *(const bf16x8*)(wp + ((kc * 4 + w) * 2 + 1) * 512);
#pragma unroll
        for (int nt = 0; nt < 2; nt++) {
            const unsigned* bp = Hs + (kc * 32 + quad * 8) * 33 + nt * 16 + nl;
            bf16x8 bh, bl; frag_packed<33>(bp, bh, bl);
            a2[nt] = MFMA(wh, bh, a2[nt]);
            a2[nt] = MFMA(wh, bl, a2[nt]);
            a2[nt] = MFMA(wl, bh, a2[nt]);
        }
    }
#pragma unroll
    for (int reg = 0; reg < 4; reg++) {
        const int f = 16 * w + quad * 4 + reg;
        const float bv = e2b[f];
#pragma unroll
        for (int nt = 0; nt < 2; nt++)
            h0[((size_t)(b * 64 + f) << 12) + row * 64 + gc + nt * 16 + nl] =
                fmaxf(a2[nt][reg] + bv, 0.f);
    }
}

// ---- GNN layer: 32-node tiles, grid 2048, quarter pipeline, drain-free ----
template <int K, bool MEAN>
__global__ __launch_bounds__(256, 6) void gnn_kernel(
    const float* __restrict__ hin, const ushort* __restrict__ wf,
    const float* __restrict__ bias, float* __restrict__ hout,
    float* __restrict__ gsum)
{
    constexpr int NQ = K / 32;
    __shared__ unsigned As[2][32 * 33];   // packed hi|lo, [k][n] stride 33, dbuf
    const int blk = blockIdx.x, tid = threadIdx.x;
    const int bid = ((blk & 7) << 8) | (blk >> 3);   // XCD-contig remap
    const int b = bid >> 7, row = (bid >> 1) & 63, tile = bid & 1;
    const int gc = tile << 5;
    const int lane = tid & 63, w = tid >> 6, quad = lane >> 4, nl = lane & 15;
    const int kq = tid >> 3, nq8 = tid & 7, n0 = nq8 * 4;
    const int hoff = tile ? -1 : 32;      // halo column (block-uniform, always valid)
    const float* hb = hin + (size_t)b * K * 4096;
    const int rowu = (row > 0) ? row - 1 : row;
    const int rowd = (row < 63) ? row + 1 : row;
    const float su = (row > 0) ? 1.f : 0.f;
    const float sd = (row < 63) ? 1.f : 0.f;
    float inv[4];
#pragma unroll
    for (int i = 0; i < 4; i++) {
        const int n = gc + n0 + i;
        const int deg = (row > 0) + (row < 63) + (n > 0) + (n < 63);
        inv[i] = 1.f / ((float)deg + 1e-6f);
    }

    const ushort* wfl = wf + lane * 8;
    f32x4 acc[2][2];
#pragma unroll
    for (int nt = 0; nt < 2; nt++) {
        acc[nt][0] = (f32x4){0.f, 0.f, 0.f, 0.f};
        acc[nt][1] = (f32x4){0.f, 0.f, 0.f, 0.f};
    }

    float4 S0, S1, S2; float S3;   // one quarter's staging (13 VGPR)
    bf16x8 V[2][2];

    auto sload = [&](int q) {
        const int k = q * 32 + kq;
        const float* pc = hb + ((size_t)k << 12) + row * 64 + gc;
        S0 = *(const float4*)(pc + n0);
        S1 = *(const float4*)(hb + ((size_t)k << 12) + rowu * 64 + gc + n0);
        S2 = *(const float4*)(hb + ((size_t)k << 12) + rowd * 64 + gc + n0);
        S3 = pc[hoff];                      // halo col (uniform per k-row)
    };
    auto wload = [&](int q) {
#pragma unroll
        for (int ftl = 0; ftl < 2; ftl++) {
            V[ftl][0] = *(const bf16x8*)(wfl + ((q * 8 + 2 * w + ftl) * 2) * 512);
            V[ftl][1] = *(const bf16x8*)(wfl + ((q * 8 + 2 * w + ftl) * 2 + 1) * 512);
        }
    };
    auto stage = [&](unsigned* Ab) {
        const float pw = __shfl_up(S0.w, 1);
        const float nx = __shfl_down(S0.x, 1);
        const float eL = tile ? S3 : 0.f;   // tile1: left halo = col 31
        const float eR = tile ? 0.f : S3;   // tile0: right halo = col 32
        const float lx = (nq8 > 0) ? pw : eL;
        const float rw = (nq8 < 7) ? nx : eR;
        unsigned* ap = Ab + kq * 33 + n0;
        ap[0] = pack_split((su * S1.x + sd * S2.x + lx + S0.y) * inv[0]);
        ap[1] = pack_split((su * S1.y + sd * S2.y + S0.x + S0.z) * inv[1]);
        ap[2] = pack_split((su * S1.z + sd * S2.z + S0.y + S0.w) * inv[2]);
        ap[3] = pack_split((su * S1.w + sd * S2.w + S0.z + rw) * inv[3]);
    };
    auto consume = [&](const unsigned* Ab) {
#pragma unroll
        for (int nt = 0; nt < 2; nt++) {
            const unsigned* bp = Ab + (quad * 8) * 33 + nt * 16 + nl;
            bf16x8 bh, bl; frag_packed<33>(bp, bh, bl);
            acc[nt][0] = MFMA(V[0][0], bh, acc[nt][0]);
            acc[nt][0] = MFMA(V[0][0], bl, acc[nt][0]);
            acc[nt][0] = MFMA(V[0][1], bh, acc[nt][0]);
            acc[nt][1] = MFMA(V[1][0], bh, acc[nt][1]);
            acc[nt][1] = MFMA(V[1][0], bl, acc[nt][1]);
            acc[nt][1] = MFMA(V[1][1], bh, acc[nt][1]);
        }
    };

    // prologue
    wload(0);
    sload(0);
    stage(As[0]);
    sload(1);
    block_sync_lgkm();

#pragma unroll
    for (int q = 0; q < NQ; q++) {
        consume(As[q & 1]);                    // waits V(q): older sloads stay in flight
        if (q + 1 < NQ) {
            wload(q + 1);
            stage(As[(q + 1) & 1]);            // waits S(q+1)
            if (q + 2 < NQ) sload(q + 2);      // refill S
            block_sync_lgkm();                 // LDS visible; globals in flight
        }
    }

    // ---- epilogue: + rowsum*bias, relu ----
    if (!MEAN) {
#pragma unroll
        for (int ftl = 0; ftl < 2; ftl++) {
            const int fb = 32 * w + 16 * ftl + quad * 4;
            const float b0 = bias[fb], b1 = bias[fb + 1], b2 = bias[fb + 2], b3 = bias[fb + 3];
#pragma unroll
            for (int nt = 0; nt < 2; nt++) {
                const int n = gc + nt * 16 + nl;
                const int deg = (row > 0) + (row < 63) + (n > 0) + (n < 63);
                const float rs = (float)deg / ((float)deg + 1e-6f);
                float* op = hout + ((size_t)(b * 128 + fb) << 12) + row * 64 + n;
                op[0]        = fmaxf(acc[nt][ftl][0] + rs * b0, 0.f);
                op[1u << 12] = fmaxf(acc[nt][ftl][1] + rs * b1, 0.f);
                op[2u << 12] = fmaxf(acc[nt][ftl][2] + rs * b2, 0.f);
                op[3u << 12] = fmaxf(acc[nt][ftl][3] + rs * b3, 0.f);
            }
        }
    } else {
#pragma unroll
        for (int ftl = 0; ftl < 2; ftl++) {
            const int fb = 32 * w + 16 * ftl + quad * 4;
#pragma unroll
            for (int reg = 0; reg < 4; reg++) {
                const float bv = bias[fb + reg];
                float v = 0.f;
#pragma unroll
                for (int nt = 0; nt < 2; nt++) {
                    const int n = gc + nt * 16 + nl;
                    const int deg = (row > 0) + (row < 63) + (n > 0) + (n < 63);
                    const float rs = (float)deg / ((float)deg + 1e-6f);
                    v += fmaxf(acc[nt][ftl][reg] + rs * bv, 0.f);
                }
                v += __shfl_xor(v, 1); v += __shfl_xor(v, 2);
                v += __shfl_xor(v, 4); v += __shfl_xor(v, 8);
                if (nl == 0) atomicAdd(&gsum[b * 128 + fb + reg], v * (1.f / 4096.f));
            }
        }
    }
}

// ---- readout: per-batch block, 2-layer MLP (fp32 vector) ----
__global__ __launch_bounds__(256) void readout_kernel(
    const float* __restrict__ gsum, const float* __restrict__ r1w,
    const float* __restrict__ r1b, const float* __restrict__ r2w,
    const float* __restrict__ r2b, float* __restrict__ out)
{
    __shared__ float gs[128];
    __shared__ float g2[256];
    const int b = blockIdx.x, tid = threadIdx.x;
    if (tid < 128) gs[tid] = gsum[b * 128 + tid];
    __syncthreads();
    float a = r1b[tid];
#pragma unroll 16
    for (int k = 0; k < 128; k++) a = fmaf(gs[k], r1w[k * 256 + tid], a);
    g2[tid] = fmaxf(a, 0.f);
    __syncthreads();
    float a2 = r2b[tid];
#pragma unroll 16
    for (int k = 0; k < 256; k++) a2 = fmaf(g2[k], r2w[k * 256 + tid], a2);
    out[b * 256 + tid] = fmaxf(a2, 0.f);
}

extern "C" void kernel_launch(void* const* d_in, const int* in_sizes, int n_in,
                              void* d_out, int out_size, void* d_ws, size_t ws_size,
                              hipStream_t stream)
{
    const float* obs = (const float*)d_in[0];
    const float* e1w = (const float*)d_in[1];
    const float* e1b = (const float*)d_in[2];
    const float* e2w = (const float*)d_in[3];
    const float* e2b = (const float*)d_in[4];
    const float* g1w = (const float*)d_in[5];
    const float* g1b = (const float*)d_in[6];
    const float* g2w = (const float*)d_in[7];
    const float* g2b = (const float*)d_in[8];
    const float* g3w = (const float*)d_in[9];
    const float* g3b = (const float*)d_in[10];
    const float* r1w = (const float*)d_in[11];
    const float* r1b = (const float*)d_in[12];
    const float* r2w = (const float*)d_in[13];
    const float* r2b = (const float*)d_in[14];
    float* out = (float*)d_out;
    float* ws = (float*)d_ws;

    float* h0 = ws;                                   // 16 MB
    float* h1 = ws + 4194304;                         // 32 MB
    float* h2 = ws + 4194304 + 8388608;               // 32 MB
    float* gsum = (float*)((char*)d_ws + 80u * 1024u * 1024u);          // 8 KB
    ushort* wfb = (ushort*)((char*)d_ws + 80u * 1024u * 1024u + 8192u); // 184 KB

    hipLaunchKernelGGL(wprep_kernel, dim3(124), dim3(64), 0, stream,
                       e1w, e2w, g1w, g2w, g3w, wfb, gsum);
    hipLaunchKernelGGL(embed_kernel, dim3(2048), dim3(256), 0, stream,
                       obs, wfb, e1b, e2b, h0);
    hipLaunchKernelGGL((gnn_kernel<64, false>), dim3(2048), dim3(256), 0, stream,
                       h0, wfb + 12288, g1b, h1, nullptr);
    hipLaunchKernelGGL((gnn_kernel<128, false>), dim3(2048), dim3(256), 0, stream,
                       h1, wfb + 28672, g2b, h2, nullptr);
    hipLaunchKernelGGL((gnn_kernel<128, true>), dim3(2048), dim3(256), 0, stream,
                       h2, wfb + 61440, g3b, nullptr, gsum);
    hipLaunchKernelGGL(readout_kernel, dim3(16), dim3(256), 0, stream,
                       gsum, r1w, r1b, r2w, r2b, out);
}